// Round 14
// baseline (155.822 us; speedup 1.0000x reference)
//
#include <hip/hip_runtime.h>
#include <math.h>

#define B_  32
#define N_  256
#define K_  8
#define HW_ 196
#define C_  1000
#define D_  50176            // N_*HW_
#define WK_ 12845056         // N_*N_*HW_ per k

// ws float offsets
#define WS_AH   0            // B*K*HW = 50176 floats
#define WS_DR   50176        // B*K*N  = 65536 floats
#define WS_PART 115712       // 128*49*4*256 = 6422528 floats
#define WS_ABF  6538240      // bf16 A matrix: 6422528 shorts (3211264 float slots)
#define WS_LOG  9749504      // logits: B*K*HW = 50176 floats

// dim_red tiling: 49 chunks x 4 m-groups x 8 k = 1568 blocks; 4 phases of 16 rows
#define NCH 49
#define CHD 1024             // d per chunk (4 KB per row = one DRAM page)
#define NPH 4

typedef __attribute__((ext_vector_type(8))) short short8;
typedef __attribute__((ext_vector_type(4))) float f32x4;
typedef __attribute__((ext_vector_type(2))) unsigned uint2v;
typedef unsigned short bf16u;   // bf16 as raw bits

// fp32 -> bf16 RNE, packed pair into u32
__device__ __forceinline__ unsigned pk2(float a, float b) {
  unsigned ua = __builtin_bit_cast(unsigned, a);
  unsigned ub = __builtin_bit_cast(unsigned, b);
  ua = (ua + 0x7fffu + ((ua >> 16) & 1u)) >> 16;
  ub = (ub + 0x7fffu + ((ub >> 16) & 1u)) & 0xffff0000u;
  return ub | ua;
}

// ---------------- kernel 1a: logits (1x1 conv), grid (32 b, 8 k) ----------------
__global__ __launch_bounds__(256) void k_logits(const float* __restrict__ x,
                                                const float* __restrict__ cw,
                                                float* __restrict__ ws) {
  const int b = blockIdx.x, k = blockIdx.y;
  const int t = threadIdx.x;
  __shared__ float cwl[N_];
  cwl[t] = cw[k*N_ + t];
  __syncthreads();
  if (t < HW_) {
    const float* xb = x + (size_t)b*D_ + t;
    float acc = 0.f;
#pragma unroll 8
    for (int n = 0; n < N_; ++n) acc = fmaf(xb[(size_t)n*HW_], cwl[n], acc);
    ws[WS_LOG + (b*K_ + k)*HW_ + t] = acc;
  }
}

// ---------------- kernel 1b: softmax over k + loss, grid 32 ----------------
__global__ __launch_bounds__(256) void k_smloss(float* __restrict__ ws,
                                                float* __restrict__ out) {
  const int b = blockIdx.x, t = threadIdx.x;
  __shared__ float AH[K_][HW_ + 4];
  __shared__ float red[256];
  if (t < HW_) {
    float v[K_]; float m = -1e30f;
#pragma unroll
    for (int k = 0; k < K_; ++k) { v[k] = ws[WS_LOG + (b*K_ + k)*HW_ + t]; m = fmaxf(m, v[k]); }
    float s = 0.f;
#pragma unroll
    for (int k = 0; k < K_; ++k) { v[k] = __expf(v[k] - m); s += v[k]; }
    const float inv = 1.f / s;
#pragma unroll
    for (int k = 0; k < K_; ++k) {
      const float a = v[k] * inv;
      AH[k][t] = a;
      ws[WS_AH + (b*K_ + k)*HW_ + t] = a;
    }
  }
  __syncthreads();
  float l = 0.f;
  if (t < HW_) {                       // G[w,v] contribution
    const int w = t / 14, v2 = t % 14;
    float g = 0.f;
#pragma unroll
    for (int k = 0; k < K_; ++k)
#pragma unroll
      for (int h = 0; h < 14; ++h)
        g = fmaf(AH[k][h*14 + w], AH[k][h*14 + v2], g);
    l = g * g;
  }
  if (t < 112) {                       // loss2
    const int k2 = t / 14, w = t % 14;
    float s = 0.f;
#pragma unroll
    for (int h = 0; h < 14; ++h) s += AH[k2][h*14 + w];
    l -= s * s;
  }
  red[t] = l;
  __syncthreads();
  for (int s2 = 128; s2 > 0; s2 >>= 1) { if (t < s2) red[t] += red[t + s2]; __syncthreads(); }
  if (t == 0) out[256256 + b] = red[0];
}

// ---------------- kernel 1c: materialize A = x*ah as bf16  [B*K, D] ----------------
__global__ __launch_bounds__(256) void k_amat(const float* __restrict__ x,
                                              const float* __restrict__ ah,
                                              bf16u* __restrict__ abf) {
  const int chunk = blockIdx.x, b = blockIdx.y;
  const int t = threadIdx.x;
  __shared__ float ahl[K_][HW_ + 4];
  if (t < HW_) {
#pragma unroll
    for (int k = 0; k < K_; ++k) ahl[k][t] = ah[(b*K_ + k)*HW_ + t];
  }
  const int d = chunk*CHD + t*4;
  const float4 xv = *(const float4*)(x + (size_t)b*D_ + d);
  int h0 = d % HW_;
  int h1 = h0 + 1; if (h1 >= HW_) h1 -= HW_;
  int h2 = h0 + 2; if (h2 >= HW_) h2 -= HW_;
  int h3 = h0 + 3; if (h3 >= HW_) h3 -= HW_;
  __syncthreads();
#pragma unroll
  for (int k = 0; k < K_; ++k) {
    uint2v v;
    v.x = pk2(xv.x*ahl[k][h0], xv.y*ahl[k][h1]);
    v.y = pk2(xv.z*ahl[k][h2], xv.w*ahl[k][h3]);
    __builtin_nontemporal_store(v, (uint2v*)(abf + (size_t)(b*K_ + k)*D_ + d));
  }
}

// ---------------- kernel 2: dim_red — split cache policy on W stream ----------------
// mg<2 half (205 MB) via cacheable loads -> L3-resident across graph replays (low latency);
// mg>=2 half via non-temporal (bypass, doesn't thrash the resident half).
__global__ __launch_bounds__(256, 2) void k_dimred(const float* __restrict__ dw,
                                                   const bf16u* __restrict__ abf,
                                                   float* __restrict__ part) {
  const int bid = blockIdx.x;
  const int c    = bid % NCH;
  const int band = bid / NCH;
  const int mg   = band & 3;
  const int k    = band >> 2;
  const int t = threadIdx.x;
  const int lane = t & 63, wv = t >> 6;
  const int r = lane & 15, g = lane >> 4;
  const int h = wv & 1, q = wv >> 1;

  __shared__ __align__(16) char Wb[2][16*2048];   // [buf][row][2048B], 16B-slot XOR swizzle

  // ---- A fragments for this wave's (h, q): 16 d-slices, loaded once (cacheable: L3 reuse) ----
  uint4 ar[16];
  {
    const bf16u* ab = abf + ((size_t)((h*16 + r)*K_ + k))*D_ + c*CHD + q*512 + g*8;
#pragma unroll
    for (int s = 0; s < 16; ++s) ar[s] = *(const uint4*)(ab + s*32);
  }

  const float* wbase = dw + (size_t)k*WK_ + (size_t)(mg*64)*D_ + c*CHD + t*4;
  const int rbase = r*2048;
  const int rswz  = (r & 7) << 4;
  const bool cacheable = (mg < 2);

  f32x4 wr[16];

  auto load_ph_c = [&](int p) {        // cacheable: allocate -> L3-resident across replays
    const float* wp = wbase + (size_t)(p*16)*D_;
#pragma unroll
    for (int i = 0; i < 16; ++i) wr[i] = *(const f32x4*)(wp + (size_t)i*D_);
  };
  auto load_ph_nt = [&](int p) {       // streaming: bypass cache allocation
    const float* wp = wbase + (size_t)(p*16)*D_;
#pragma unroll
    for (int i = 0; i < 16; ++i)
      wr[i] = __builtin_nontemporal_load((const f32x4*)(wp + (size_t)i*D_));
  };
  auto store_ph = [&](int buf) {
    char* lb = &Wb[buf][0];
#pragma unroll
    for (int i = 0; i < 16; ++i) {
      unsigned vx = pk2(wr[i].x, wr[i].y);
      unsigned vy = pk2(wr[i].z, wr[i].w);
      uint2v v; v.x = vx; v.y = vy;
      *(uint2v*)(lb + i*2048 + ((t*8) ^ ((i & 7) << 4))) = v;
    }
  };

  // ---- prologue ----
  if (cacheable) load_ph_c(0); else load_ph_nt(0);
  store_ph(0);
  __syncthreads();

  // ---- 4 phases: prefetch(p+1) || MFMA(p) || store(p+1) ----
  for (int p = 0; p < NPH; ++p) {
    const int cur = p & 1;
    if (p < NPH - 1) { if (cacheable) load_ph_c(p + 1); else load_ph_nt(p + 1); }
    f32x4 acc = {0.f, 0.f, 0.f, 0.f};
    const char* lb = &Wb[cur][0] + rbase;
#pragma unroll
    for (int s = 0; s < 16; ++s) {
      const short8 wf = *(const short8*)(lb + ((q*1024 + s*64 + g*16) ^ rswz));
      const short8 af = __builtin_bit_cast(short8, ar[s]);
      acc = __builtin_amdgcn_mfma_f32_16x16x32_bf16(af, wf, acc, 0, 0, 0);
    }
    {   // partial entry (k, tm, c, q, h): nt scalar stores (read back only by k_reduce)
      const int tm = mg*4 + p;
      float* po = part + ((size_t)(((k*16 + tm)*NCH + c)*2 + q)*2 + h)*256;
#pragma unroll
      for (int rr = 0; rr < 4; ++rr)
        __builtin_nontemporal_store(acc[rr], po + rr*64 + lane);
    }
    if (p < NPH - 1) store_ph(cur ^ 1);
    __syncthreads();
  }
}

// ---------------- kernel 2b: reduce 49 chunks x 2 q -> dr (contiguous reads) ----------------
__global__ __launch_bounds__(256) void k_reduce(const float* __restrict__ part,
                                                float* __restrict__ dr) {
  const int blk = blockIdx.x;          // 128 = k*16 + tm
  const int k = blk >> 4, tm = blk & 15;
  const int t = threadIdx.x;
  const float* base = part + (size_t)(k*16 + tm)*NCH*4*256;
  float a0 = 0.f, a1 = 0.f;
  for (int c = 0; c < NCH; ++c) {
    const float* pc = base + c*4*256;  // entry (c, q, h): offset (q*2+h)*256
    a0 += pc[t]       + pc[512 + t];
    a1 += pc[256 + t] + pc[768 + t];
  }
  const int rr = t >> 6, g = (t >> 4) & 3, r = t & 15;
  const int m = tm*16 + r;
  dr[((g*4 + rr)*K_ + k)*N_ + m]        = a0;   // h=0 -> b = g*4+rr
  dr[((16 + g*4 + rr)*K_ + k)*N_ + m]   = a1;   // h=1 -> b = 16+g*4+rr
}

// ---------------- kernel 3: hyp = dr@Wo^T + b ; conf = tanh(dr@Wg + b) ----------------
__global__ __launch_bounds__(256) void k_out(const float* __restrict__ dr,
                                             const float* __restrict__ db,
                                             const float* __restrict__ Wo,
                                             const float* __restrict__ Wob,
                                             const float* __restrict__ Wg,
                                             const float* __restrict__ Wgb,
                                             float* __restrict__ out) {
  const int ct = blockIdx.x, k = blockIdx.y;
  const int t = threadIdx.x;
  __shared__ float Wl[32][257];
  __shared__ float dl[256][36];
#pragma unroll
  for (int i = 0; i < 32; ++i) {
    const int e = i*256 + t;
    const int row = e >> 8, col = e & 255;
    const int c = ct*32 + row;
    Wl[row][col] = (c < C_) ? Wo[((size_t)(k*C_ + c))*N_ + col] : 0.f;
  }
#pragma unroll
  for (int i = 0; i < 32; ++i) {
    const int e = i*256 + t;
    const int n = e & 255, b = e >> 8;
    dl[n][b] = dr[(b*K_ + k)*N_ + n] + db[k*N_ + n];
  }
  __syncthreads();
  const int tc = t & 31, tg = t >> 5;
  const int c = ct*32 + tc;
  float a0=0.f, a1=0.f, a2=0.f, a3=0.f;
#pragma unroll 8
  for (int n = 0; n < N_; ++n) {
    const float wvv = Wl[tc][n];
    const float4 dv = *(const float4*)&dl[n][tg*4];
    a0 = fmaf(wvv, dv.x, a0);
    a1 = fmaf(wvv, dv.y, a1);
    a2 = fmaf(wvv, dv.z, a2);
    a3 = fmaf(wvv, dv.w, a3);
  }
  if (c < C_) {
    const float bias = Wob[k*C_ + c];
    out[((size_t)(tg*4 + 0)*K_ + k)*C_ + c] = a0 + bias;
    out[((size_t)(tg*4 + 1)*K_ + k)*C_ + c] = a1 + bias;
    out[((size_t)(tg*4 + 2)*K_ + k)*C_ + c] = a2 + bias;
    out[((size_t)(tg*4 + 3)*K_ + k)*C_ + c] = a3 + bias;
  }
  if (ct == 0 && t < B_) {
    float s = Wgb[k];
    for (int n = 0; n < N_; ++n) s = fmaf(dl[n][t], Wg[k*N_ + n], s);
    out[256000 + t*K_ + k] = tanhf(s);
  }
}

extern "C" void kernel_launch(void* const* d_in, const int* in_sizes, int n_in,
                              void* d_out, int out_size, void* d_ws, size_t ws_size,
                              hipStream_t stream) {
  const float* x   = (const float*)d_in[0];
  const float* cw  = (const float*)d_in[1];
  const float* dw  = (const float*)d_in[2];
  const float* db  = (const float*)d_in[3];
  const float* Wo  = (const float*)d_in[4];
  const float* Wob = (const float*)d_in[5];
  const float* Wg  = (const float*)d_in[6];
  const float* Wgb = (const float*)d_in[7];
  float* out = (float*)d_out;
  float* ws  = (float*)d_ws;
  bf16u* abf = (bf16u*)(ws + WS_ABF);

  k_logits<<<dim3(32, 8), 256, 0, stream>>>(x, cw, ws);
  k_smloss<<<32, 256, 0, stream>>>(ws, out);
  k_amat<<<dim3(NCH, B_), 256, 0, stream>>>(x, ws + WS_AH, abf);
  k_dimred<<<NCH*4*K_, 256, 0, stream>>>(dw, abf, ws + WS_PART);
  k_reduce<<<128, 256, 0, stream>>>(ws + WS_PART, ws + WS_DR);
  k_out<<<dim3(32, 8), 256, 0, stream>>>(ws + WS_DR, db, Wo, Wob, Wg, Wgb, out);
}

// Round 15
// 138.011 us; speedup vs baseline: 1.1291x; 1.1291x over previous
//
#include <hip/hip_runtime.h>
#include <math.h>

#define B_  32
#define N_  256
#define K_  8
#define HW_ 196
#define C_  1000
#define D_  50176            // N_*HW_
#define WK_ 12845056         // N_*N_*HW_ per k

// ws float offsets
#define WS_AH   0            // B*K*HW = 50176 floats
#define WS_DR   50176        // B*K*N  = 65536 floats
#define WS_PART 115712       // 128*49*4*256 = 6422528 floats
#define WS_ABF  6538240      // bf16 A matrix: 6422528 shorts (3211264 float slots)
#define WS_LOG  9749504      // logits: B*K*HW = 50176 floats

// dim_red tiling: 49 chunks x 4 m-groups x 8 k = 1568 blocks; 4 phases of 16 rows
#define NCH 49
#define CHD 1024             // d per chunk (4 KB per row = one DRAM page)
#define NPH 4

typedef __attribute__((ext_vector_type(8))) short short8;
typedef __attribute__((ext_vector_type(4))) float f32x4;
typedef __attribute__((ext_vector_type(2))) unsigned uint2v;
typedef unsigned short bf16u;   // bf16 as raw bits

// fp32 -> bf16 RNE, packed pair into u32
__device__ __forceinline__ unsigned pk2(float a, float b) {
  unsigned ua = __builtin_bit_cast(unsigned, a);
  unsigned ub = __builtin_bit_cast(unsigned, b);
  ua = (ua + 0x7fffu + ((ua >> 16) & 1u)) >> 16;
  ub = (ub + 0x7fffu + ((ub >> 16) & 1u)) & 0xffff0000u;
  return ub | ua;
}

// ---------------- kernel 1a: logits (1x1 conv), grid (32 b, 8 k) ----------------
__global__ __launch_bounds__(256) void k_logits(const float* __restrict__ x,
                                                const float* __restrict__ cw,
                                                float* __restrict__ ws) {
  const int b = blockIdx.x, k = blockIdx.y;
  const int t = threadIdx.x;
  __shared__ float cwl[N_];
  cwl[t] = cw[k*N_ + t];
  __syncthreads();
  if (t < HW_) {
    const float* xb = x + (size_t)b*D_ + t;
    float acc = 0.f;
#pragma unroll 8
    for (int n = 0; n < N_; ++n) acc = fmaf(xb[(size_t)n*HW_], cwl[n], acc);
    ws[WS_LOG + (b*K_ + k)*HW_ + t] = acc;
  }
}

// ---------------- kernel 1b: softmax over k + loss, grid 32 ----------------
__global__ __launch_bounds__(256) void k_smloss(float* __restrict__ ws,
                                                float* __restrict__ out) {
  const int b = blockIdx.x, t = threadIdx.x;
  __shared__ float AH[K_][HW_ + 4];
  __shared__ float red[256];
  if (t < HW_) {
    float v[K_]; float m = -1e30f;
#pragma unroll
    for (int k = 0; k < K_; ++k) { v[k] = ws[WS_LOG + (b*K_ + k)*HW_ + t]; m = fmaxf(m, v[k]); }
    float s = 0.f;
#pragma unroll
    for (int k = 0; k < K_; ++k) { v[k] = __expf(v[k] - m); s += v[k]; }
    const float inv = 1.f / s;
#pragma unroll
    for (int k = 0; k < K_; ++k) {
      const float a = v[k] * inv;
      AH[k][t] = a;
      ws[WS_AH + (b*K_ + k)*HW_ + t] = a;
    }
  }
  __syncthreads();
  float l = 0.f;
  if (t < HW_) {                       // G[w,v] contribution
    const int w = t / 14, v2 = t % 14;
    float g = 0.f;
#pragma unroll
    for (int k = 0; k < K_; ++k)
#pragma unroll
      for (int h = 0; h < 14; ++h)
        g = fmaf(AH[k][h*14 + w], AH[k][h*14 + v2], g);
    l = g * g;
  }
  if (t < 112) {                       // loss2
    const int k2 = t / 14, w = t % 14;
    float s = 0.f;
#pragma unroll
    for (int h = 0; h < 14; ++h) s += AH[k2][h*14 + w];
    l -= s * s;
  }
  red[t] = l;
  __syncthreads();
  for (int s2 = 128; s2 > 0; s2 >>= 1) { if (t < s2) red[t] += red[t + s2]; __syncthreads(); }
  if (t == 0) out[256256 + b] = red[0];
}

// ---------------- kernel 1c: materialize A = x*ah as bf16  [B*K, D] ----------------
__global__ __launch_bounds__(256) void k_amat(const float* __restrict__ x,
                                              const float* __restrict__ ah,
                                              bf16u* __restrict__ abf) {
  const int chunk = blockIdx.x, b = blockIdx.y;
  const int t = threadIdx.x;
  __shared__ float ahl[K_][HW_ + 4];
  if (t < HW_) {
#pragma unroll
    for (int k = 0; k < K_; ++k) ahl[k][t] = ah[(b*K_ + k)*HW_ + t];
  }
  const int d = chunk*CHD + t*4;
  const float4 xv = *(const float4*)(x + (size_t)b*D_ + d);
  int h0 = d % HW_;
  int h1 = h0 + 1; if (h1 >= HW_) h1 -= HW_;
  int h2 = h0 + 2; if (h2 >= HW_) h2 -= HW_;
  int h3 = h0 + 3; if (h3 >= HW_) h3 -= HW_;
  __syncthreads();
#pragma unroll
  for (int k = 0; k < K_; ++k) {
    uint2v v;
    v.x = pk2(xv.x*ahl[k][h0], xv.y*ahl[k][h1]);
    v.y = pk2(xv.z*ahl[k][h2], xv.w*ahl[k][h3]);
    __builtin_nontemporal_store(v, (uint2v*)(abf + (size_t)(b*K_ + k)*D_ + d));
  }
}

// ---------------- kernel 2: dim_red — R13 structure: all-NT W stream (proven best) ----------------
__global__ __launch_bounds__(256, 2) void k_dimred(const float* __restrict__ dw,
                                                   const bf16u* __restrict__ abf,
                                                   float* __restrict__ part) {
  const int bid = blockIdx.x;
  const int c    = bid % NCH;
  const int band = bid / NCH;
  const int mg   = band & 3;
  const int k    = band >> 2;
  const int t = threadIdx.x;
  const int lane = t & 63, wv = t >> 6;
  const int r = lane & 15, g = lane >> 4;
  const int h = wv & 1, q = wv >> 1;

  __shared__ __align__(16) char Wb[2][16*2048];   // [buf][row][2048B], 16B-slot XOR swizzle

  // ---- A fragments for this wave's (h, q): 16 d-slices, loaded once (cacheable: L3 reuse) ----
  uint4 ar[16];
  {
    const bf16u* ab = abf + ((size_t)((h*16 + r)*K_ + k))*D_ + c*CHD + q*512 + g*8;
#pragma unroll
    for (int s = 0; s < 16; ++s) ar[s] = *(const uint4*)(ab + s*32);
  }

  const float* wbase = dw + (size_t)k*WK_ + (size_t)(mg*64)*D_ + c*CHD + t*4;
  const int rbase = r*2048;
  const int rswz  = (r & 7) << 4;

  f32x4 wr[16];

  auto load_ph = [&](int p) {          // streaming read: bypass cache allocation
    const float* wp = wbase + (size_t)(p*16)*D_;
#pragma unroll
    for (int i = 0; i < 16; ++i)
      wr[i] = __builtin_nontemporal_load((const f32x4*)(wp + (size_t)i*D_));
  };
  auto store_ph = [&](int buf) {
    char* lb = &Wb[buf][0];
#pragma unroll
    for (int i = 0; i < 16; ++i) {
      unsigned vx = pk2(wr[i].x, wr[i].y);
      unsigned vy = pk2(wr[i].z, wr[i].w);
      uint2v v; v.x = vx; v.y = vy;
      *(uint2v*)(lb + i*2048 + ((t*8) ^ ((i & 7) << 4))) = v;
    }
  };

  // ---- prologue ----
  load_ph(0);
  store_ph(0);
  __syncthreads();

  // ---- 4 phases: prefetch(p+1) || MFMA(p) || store(p+1) ----
  for (int p = 0; p < NPH; ++p) {
    const int cur = p & 1;
    if (p < NPH - 1) load_ph(p + 1);
    f32x4 acc = {0.f, 0.f, 0.f, 0.f};
    const char* lb = &Wb[cur][0] + rbase;
#pragma unroll
    for (int s = 0; s < 16; ++s) {
      const short8 wf = *(const short8*)(lb + ((q*1024 + s*64 + g*16) ^ rswz));
      const short8 af = __builtin_bit_cast(short8, ar[s]);
      acc = __builtin_amdgcn_mfma_f32_16x16x32_bf16(af, wf, acc, 0, 0, 0);
    }
    {   // partial entry (k, tm, c, q, h): nt scalar stores (read back only by k_reduce)
      const int tm = mg*4 + p;
      float* po = part + ((size_t)(((k*16 + tm)*NCH + c)*2 + q)*2 + h)*256;
#pragma unroll
      for (int rr = 0; rr < 4; ++rr)
        __builtin_nontemporal_store(acc[rr], po + rr*64 + lane);
    }
    if (p < NPH - 1) store_ph(cur ^ 1);
    __syncthreads();
  }
}

// ---------------- kernel 2b: reduce 49 chunks x 2 q -> dr (contiguous reads) ----------------
__global__ __launch_bounds__(256) void k_reduce(const float* __restrict__ part,
                                                float* __restrict__ dr) {
  const int blk = blockIdx.x;          // 128 = k*16 + tm
  const int k = blk >> 4, tm = blk & 15;
  const int t = threadIdx.x;
  const float* base = part + (size_t)(k*16 + tm)*NCH*4*256;
  float a0 = 0.f, a1 = 0.f;
  for (int c = 0; c < NCH; ++c) {
    const float* pc = base + c*4*256;  // entry (c, q, h): offset (q*2+h)*256
    a0 += pc[t]       + pc[512 + t];
    a1 += pc[256 + t] + pc[768 + t];
  }
  const int rr = t >> 6, g = (t >> 4) & 3, r = t & 15;
  const int m = tm*16 + r;
  dr[((g*4 + rr)*K_ + k)*N_ + m]        = a0;   // h=0 -> b = g*4+rr
  dr[((16 + g*4 + rr)*K_ + k)*N_ + m]   = a1;   // h=1 -> b = 16+g*4+rr
}

// ---------------- kernel 3: hyp = dr@Wo^T + b ; conf = tanh(dr@Wg + b) ----------------
__global__ __launch_bounds__(256) void k_out(const float* __restrict__ dr,
                                             const float* __restrict__ db,
                                             const float* __restrict__ Wo,
                                             const float* __restrict__ Wob,
                                             const float* __restrict__ Wg,
                                             const float* __restrict__ Wgb,
                                             float* __restrict__ out) {
  const int ct = blockIdx.x, k = blockIdx.y;
  const int t = threadIdx.x;
  __shared__ float Wl[32][257];
  __shared__ float dl[256][36];
#pragma unroll
  for (int i = 0; i < 32; ++i) {
    const int e = i*256 + t;
    const int row = e >> 8, col = e & 255;
    const int c = ct*32 + row;
    Wl[row][col] = (c < C_) ? Wo[((size_t)(k*C_ + c))*N_ + col] : 0.f;
  }
#pragma unroll
  for (int i = 0; i < 32; ++i) {
    const int e = i*256 + t;
    const int n = e & 255, b = e >> 8;
    dl[n][b] = dr[(b*K_ + k)*N_ + n] + db[k*N_ + n];
  }
  __syncthreads();
  const int tc = t & 31, tg = t >> 5;
  const int c = ct*32 + tc;
  float a0=0.f, a1=0.f, a2=0.f, a3=0.f;
#pragma unroll 8
  for (int n = 0; n < N_; ++n) {
    const float wvv = Wl[tc][n];
    const float4 dv = *(const float4*)&dl[n][tg*4];
    a0 = fmaf(wvv, dv.x, a0);
    a1 = fmaf(wvv, dv.y, a1);
    a2 = fmaf(wvv, dv.z, a2);
    a3 = fmaf(wvv, dv.w, a3);
  }
  if (c < C_) {
    const float bias = Wob[k*C_ + c];
    out[((size_t)(tg*4 + 0)*K_ + k)*C_ + c] = a0 + bias;
    out[((size_t)(tg*4 + 1)*K_ + k)*C_ + c] = a1 + bias;
    out[((size_t)(tg*4 + 2)*K_ + k)*C_ + c] = a2 + bias;
    out[((size_t)(tg*4 + 3)*K_ + k)*C_ + c] = a3 + bias;
  }
  if (ct == 0 && t < B_) {
    float s = Wgb[k];
    for (int n = 0; n < N_; ++n) s = fmaf(dl[n][t], Wg[k*N_ + n], s);
    out[256000 + t*K_ + k] = tanhf(s);
  }
}

extern "C" void kernel_launch(void* const* d_in, const int* in_sizes, int n_in,
                              void* d_out, int out_size, void* d_ws, size_t ws_size,
                              hipStream_t stream) {
  const float* x   = (const float*)d_in[0];
  const float* cw  = (const float*)d_in[1];
  const float* dw  = (const float*)d_in[2];
  const float* db  = (const float*)d_in[3];
  const float* Wo  = (const float*)d_in[4];
  const float* Wob = (const float*)d_in[5];
  const float* Wg  = (const float*)d_in[6];
  const float* Wgb = (const float*)d_in[7];
  float* out = (float*)d_out;
  float* ws  = (float*)d_ws;
  bf16u* abf = (bf16u*)(ws + WS_ABF);

  k_logits<<<dim3(32, 8), 256, 0, stream>>>(x, cw, ws);
  k_smloss<<<32, 256, 0, stream>>>(ws, out);
  k_amat<<<dim3(NCH, B_), 256, 0, stream>>>(x, ws + WS_AH, abf);
  k_dimred<<<NCH*4*K_, 256, 0, stream>>>(dw, abf, ws + WS_PART);
  k_reduce<<<128, 256, 0, stream>>>(ws + WS_PART, ws + WS_DR);
  k_out<<<dim3(32, 8), 256, 0, stream>>>(ws + WS_DR, db, Wo, Wob, Wg, Wgb, out);
}